// Round 3
// baseline (200.600 us; speedup 1.0000x reference)
//
#include <hip/hip_runtime.h>
#include <hip/hip_bf16.h>

// 3x3 conv pad=1 stride=1, NHWC fp32 -> bf16 MFMA implicit GEMM.
//   M = 32*56*56 = 100352, N = 256, K = 9*128 = 1152
// R7: one-barrier phases + cross-phase fragment prefetch.
// R6 (m201-faithful 2-barrier phases) measured 54% SIMD idle: the ds_read
// segment between closing/opening barriers is a window where ALL waves read
// and the MFMA pipe idles, globally serialized by the barrier pair.  R7 moves
// each phase's fragment reads into the PREVIOUS phase's post-MFMA slot (after
// its counted VMWAIT) so reads overlap other waves' MFMA windows, and drops
// to ONE barrier per phase (the closing barrier alone enforces WAR-before-
// stage and VMWAIT-before-read across waves).
// vmcnt ledger (steady state, 2 loads/stage, 1 stage/phase, drains of 4 at
// P1/P3/P5/P7 via VMWAIT(6)): entering an iteration 8 outstanding =
// {A(kt,1),B(kt,1),A(kt+1,0),B(kt+1,0)}.  P1 drains buf0-kh1 (read at
// P2-post), P3 drains buf1-kh0 (P4-post), P5 drains buf1-kh1 (P6-post),
// P7 drains next buf0-kh0 (P8-post).  Every stage-overwrite of a region is
// >=1 barrier after that region's last ds_read (checked per-phase).  Fragment
// sets double-named (M0a/M0b, M1a/M1b, Ba/Bb) with disjoint live ranges so
// the allocator coalesces them (static indexing only, rule #20).

#define NIMG 32
#define HH 56
#define WW 56
#define PH 58
#define PW 58
#define CIN 128
#define COUT 256
#define KTOT 1152
#define PAD_ELEMS (NIMG * PH * PW * CIN)

#define BM 224
#define BK 64
#define NT (KTOT / BK)                   // 18 K-tiles
#define NBLK ((NIMG * HH * WW) / BM)     // 448 = 8 * 56

#define AREG_SZ 7168
#define BREG_BASE 28672
#define BREG_SZ 8192

typedef __attribute__((ext_vector_type(8))) short bf16x8;
typedef __attribute__((ext_vector_type(4))) short s16x4;
typedef __attribute__((ext_vector_type(4))) float f32x4;

__device__ __forceinline__ short f2bf(float x) {
    union { __hip_bfloat16 b; short s; } u;
    u.b = __float2bfloat16(x);
    return u.s;
}

typedef const void __attribute__((address_space(1)))* gas1_t;
typedef void __attribute__((address_space(3)))* las3_t;
__device__ __forceinline__ void async16(short* lds_p, const short* g) {
    __builtin_amdgcn_global_load_lds((gas1_t)g, (las3_t)lds_p, 16, 0, 0);
}

// ---- pack 1: fp32 NHWC -> padded bf16 (32,58,58,128), zero halo -------------
__global__ __launch_bounds__(256) void pack_input(const float* __restrict__ in,
                                                  short* __restrict__ pad) {
    const int tid  = blockIdx.x * 256 + threadIdx.x;
    const int flat = tid * 8;
    const int c8   = flat & (CIN - 1);
    const int rest = flat >> 7;
    const int iw   = rest % PW;
    const int r2   = rest / PW;
    const int ih   = r2 % PH;
    const int img  = r2 / PH;
    bf16x8 v = (bf16x8)0;
    if (ih >= 1 && ih <= HH && iw >= 1 && iw <= WW) {
        const float* p = in + (((size_t)(img * HH + ih - 1) * WW + (iw - 1)) * CIN + c8);
        const float4 x0 = *(const float4*)p;
        const float4 x1 = *(const float4*)(p + 4);
        v.s0 = f2bf(x0.x); v.s1 = f2bf(x0.y); v.s2 = f2bf(x0.z); v.s3 = f2bf(x0.w);
        v.s4 = f2bf(x1.x); v.s5 = f2bf(x1.y); v.s6 = f2bf(x1.z); v.s7 = f2bf(x1.w);
    }
    *(bf16x8*)(pad + flat) = v;
}

// ---- pack 2: weights (K=1152, N=256) fp32 -> bf16 transposed [n][k] ---------
__global__ __launch_bounds__(256) void pack_wgt(const float* __restrict__ w,
                                                short* __restrict__ wt) {
    __shared__ short tile[32][33];
    const int k0 = blockIdx.x * 32;
    const int n0 = blockIdx.y * 32;
    const int t  = threadIdx.x;
    {
        const int kl  = t >> 3;
        const int nl4 = (t & 7) * 4;
        const float4 x = *(const float4*)(w + (size_t)(k0 + kl) * COUT + n0 + nl4);
        tile[kl][nl4 + 0] = f2bf(x.x);
        tile[kl][nl4 + 1] = f2bf(x.y);
        tile[kl][nl4 + 2] = f2bf(x.z);
        tile[kl][nl4 + 3] = f2bf(x.w);
    }
    __syncthreads();
    {
        const int nl  = t >> 3;
        const int kl4 = (t & 7) * 4;
        s16x4 v;
        v.x = tile[kl4 + 0][nl];
        v.y = tile[kl4 + 1][nl];
        v.z = tile[kl4 + 2][nl];
        v.w = tile[kl4 + 3][nl];
        *(s16x4*)(wt + (size_t)(n0 + nl) * KTOT + k0 + kl4) = v;
    }
}

// ---- GEMM: 224x256 tile, BK=64, 1-barrier phases, 16x16x32 bf16 MFMA --------
#define FENCE() asm volatile("" ::: "memory")
#define BARRIER() do { FENCE(); __builtin_amdgcn_s_barrier(); FENCE(); } while (0)
#define VMWAIT(N) asm volatile("s_waitcnt vmcnt(" #N ")" ::: "memory")

__global__ __launch_bounds__(512, 2) void conv_mfma(const short* __restrict__ apad,
                                                    const short* __restrict__ bwt,
                                                    const float* __restrict__ bias,
                                                    float* __restrict__ out) {
    __shared__ short lds[61440];   // 120 KiB

    const int t  = threadIdx.x;    // 0..511
    const int l  = t & 63;
    const int w  = t >> 6;         // 0..7
    const int wm = w >> 2;         // 0..1  (M half: 112 rows)
    const int wn = w & 3;          // 0..3  (N quarter: 64 cols)
    const int fr = l & 15;
    const int fq = l >> 4;

    // fragment lane offset (shorts), swizzle folded in (frag row base is a
    // multiple of 16 so (row>>1)&3 == (fr>>1)&3):
    const int laneoff = fr * 32 + ((fq ^ ((fr >> 1) & 3))) * 8;
    const int afb = wm * 3584;     // A frag base: (wm*112)*32 shorts
    const int bfb = wn * 2048;     // B frag base: (wn*64)*32 shorts
    // staging: thread t -> row t>>2, phys chunk t&3; logical kchunk
    // kc = (t&3) ^ ((row>>1)&3) = (t&3) ^ ((t>>3)&3)
    const int kcs = (t & 3) ^ ((t >> 3) & 3);

    const int bid = blockIdx.x;
    const int swz = (bid & 7) * (NBLK / 8) + (bid >> 3);   // 448 = 8*56, bijective
    const int m0  = swz * BM;

    // global row bases for staging (rows r0, and r0+128 for waves 0..5)
    const int r0 = t >> 2;         // 0..127
    int abase0, abase1;
    {
        int m = m0 + r0;
        int img = m / (HH * WW), rem = m - img * (HH * WW);
        int oh = rem / WW, ow = rem - oh * WW;
        abase0 = ((img * PH + oh) * PW + ow) * CIN;
        if (t < 384) {             // rows 128..223 (waves 0..5)
            m = m0 + r0 + 128;
            img = m / (HH * WW); rem = m - img * (HH * WW);
            oh = rem / WW; ow = rem - oh * WW;
            abase1 = ((img * PH + oh) * PW + ow) * CIN;
        } else {
            abase1 = abase0;       // waves 6,7: duplicate of load1 (dummy)
        }
    }
    const int a2lds = (w < 6) ? (4096 + w * 512) : (w * 512);
    const int bbase0 = r0 * KTOT;
    const int bbase1 = (r0 + 128) * KTOT;

    f32x4 acc[7][4];
#pragma unroll
    for (int i = 0; i < 7; ++i)
#pragma unroll
        for (int j = 0; j < 4; ++j) { f32x4 z = {0.f, 0.f, 0.f, 0.f}; acc[i][j] = z; }

    // double-named fragment sets; live ranges are disjoint -> allocator coalesces
    bf16x8 M0a[4], M0b[4], M1a[3], M1b[3], Ba[4], Bb[4];

    // K-tile KT covers tap = KT>>1 (CIN=128, BK=64), channel base (KT&1)*64.
#define STAGE_A(KT, KH) do {                                                  \
        const int _tap = (KT) >> 1;                                           \
        const int _fh  = (_tap * 11) >> 5;   /* /3 for 0..8 */                \
        const int _fw  = _tap - 3 * _fh;                                      \
        const int _off = (_fh * PW + _fw) * CIN + ((KT) & 1) * 64             \
                         + (KH) * 32 + kcs * 8;                               \
        short* _l = lds + ((((KT) & 1) << 1) + (KH)) * AREG_SZ;               \
        async16(_l + w * 512, apad + abase0 + _off);                          \
        async16(_l + a2lds,   apad + abase1 + _off);                          \
    } while (0)

#define STAGE_B(KT, KH) do {                                                  \
        const int _off = (KT) * 64 + (KH) * 32 + kcs * 8;                     \
        short* _l = lds + BREG_BASE + ((((KT) & 1) << 1) + (KH)) * BREG_SZ;   \
        async16(_l + w * 512,        bwt + bbase0 + _off);                    \
        async16(_l + 4096 + w * 512, bwt + bbase1 + _off);                    \
    } while (0)

    // fragment reads from region REG (= buf*2 + kh, 0..3)
#define RD_M0B(M0, BF, REG) do {                                              \
        const short* _a = lds + (REG) * AREG_SZ;                              \
        const short* _b = lds + BREG_BASE + (REG) * BREG_SZ;                  \
        _Pragma("unroll")                                                     \
        for (int _i = 0; _i < 4; ++_i)                                        \
            (M0)[_i] = *(const bf16x8*)(_a + afb + _i * 512 + laneoff);       \
        _Pragma("unroll")                                                     \
        for (int _j = 0; _j < 4; ++_j)                                        \
            (BF)[_j] = *(const bf16x8*)(_b + bfb + _j * 512 + laneoff);       \
    } while (0)

#define RD_M1(M1, REG) do {                                                   \
        const short* _a = lds + (REG) * AREG_SZ;                              \
        _Pragma("unroll")                                                     \
        for (int _i = 0; _i < 3; ++_i)                                        \
            (M1)[_i] = *(const bf16x8*)(_a + afb + 2048 + _i * 512 + laneoff);\
    } while (0)

#define MM0(M0, BF) do {                                                      \
        __builtin_amdgcn_s_setprio(1);                                        \
        _Pragma("unroll")                                                     \
        for (int _i = 0; _i < 4; ++_i)                                        \
            _Pragma("unroll")                                                 \
            for (int _j = 0; _j < 4; ++_j)                                    \
                acc[_i][_j] = __builtin_amdgcn_mfma_f32_16x16x32_bf16(        \
                    (M0)[_i], (BF)[_j], acc[_i][_j], 0, 0, 0);                \
        __builtin_amdgcn_s_setprio(0);                                        \
    } while (0)

#define MM1(M1, BF) do {                                                      \
        __builtin_amdgcn_s_setprio(1);                                        \
        _Pragma("unroll")                                                     \
        for (int _i = 0; _i < 3; ++_i)                                        \
            _Pragma("unroll")                                                 \
            for (int _j = 0; _j < 4; ++_j)                                    \
                acc[4 + _i][_j] = __builtin_amdgcn_mfma_f32_16x16x32_bf16(    \
                    (M1)[_i], (BF)[_j], acc[4 + _i][_j], 0, 0, 0);            \
        __builtin_amdgcn_s_setprio(0);                                        \
    } while (0)

    // prologue: 6 half-stages (12 loads); drain buf0-kh0; read P1's fragments.
    STAGE_A(0, 0); STAGE_B(0, 0);
    STAGE_A(0, 1); STAGE_B(0, 1);
    STAGE_A(1, 0); STAGE_B(1, 0);
    VMWAIT(8);
    BARRIER();
    RD_M0B(M0a, Ba, 0);

    // main loop: phase = {stage issue | MFMA(prefetched) | [VMWAIT] |
    //                     prefetch next phase's fragments | barrier}
#pragma unroll 1
    for (int kt = 0; kt < NT - 2; kt += 2) {
        STAGE_A(kt + 1, 1); MM0(M0a, Ba); VMWAIT(6); RD_M1(M1a, 0);      BARRIER();
        STAGE_B(kt + 1, 1); MM1(M1a, Ba);            RD_M0B(M0b, Bb, 1); BARRIER();
        STAGE_A(kt + 2, 0); MM0(M0b, Bb); VMWAIT(6); RD_M1(M1b, 1);      BARRIER();
        STAGE_B(kt + 2, 0); MM1(M1b, Bb);            RD_M0B(M0a, Ba, 2); BARRIER();
        STAGE_A(kt + 2, 1); MM0(M0a, Ba); VMWAIT(6); RD_M1(M1a, 2);      BARRIER();
        STAGE_B(kt + 2, 1); MM1(M1a, Ba);            RD_M0B(M0b, Bb, 3); BARRIER();
        STAGE_A(kt + 3, 0); MM0(M0b, Bb); VMWAIT(6); RD_M1(M1b, 3);      BARRIER();
        STAGE_B(kt + 3, 0); MM1(M1b, Bb);            RD_M0B(M0a, Ba, 0); BARRIER();
    }

    // tail: K-tiles 16 (regions 0,1) and 17 (regions 2,3); drains 6/4/0.
    STAGE_A(NT - 1, 1); MM0(M0a, Ba); VMWAIT(6); RD_M1(M1a, 0);      BARRIER();
    STAGE_B(NT - 1, 1); MM1(M1a, Ba);            RD_M0B(M0b, Bb, 1); BARRIER();
    MM0(M0b, Bb); VMWAIT(4); RD_M1(M1b, 1);      BARRIER();
    MM1(M1b, Bb);            RD_M0B(M0a, Ba, 2); BARRIER();
    MM0(M0a, Ba); VMWAIT(0); RD_M1(M1a, 2);      BARRIER();
    MM1(M1a, Ba);            RD_M0B(M0b, Bb, 3); BARRIER();
    MM0(M0b, Bb);            RD_M1(M1b, 3);      BARRIER();
    MM1(M1b, Bb);

    // ---- epilogue: bias + ReLU. D: col(N)=lane&15, row(M)=fq*4+reg (m89)
#pragma unroll
    for (int j = 0; j < 4; ++j) {
        const int n  = wn * 64 + j * 16 + fr;
        const float bj = bias[n];
#pragma unroll
        for (int i = 0; i < 7; ++i) {
            const int mr = m0 + wm * 112 + i * 16 + fq * 4;
#pragma unroll
            for (int r = 0; r < 4; ++r) {
                const float v = acc[i][j][r] + bj;
                out[(size_t)(mr + r) * COUT + n] = v > 0.f ? v : 0.f;
            }
        }
    }
#undef STAGE_A
#undef STAGE_B
#undef RD_M0B
#undef RD_M1
#undef MM0
#undef MM1
}

extern "C" void kernel_launch(void* const* d_in, const int* in_sizes, int n_in,
                              void* d_out, int out_size, void* d_ws, size_t ws_size,
                              hipStream_t stream) {
    const float* in   = (const float*)d_in[0];
    const float* wgt  = (const float*)d_in[1];
    const float* bias = (const float*)d_in[2];
    float* out = (float*)d_out;

    short* pad = (short*)d_ws;
    short* wt  = (short*)d_ws + PAD_ELEMS;

    pack_input<<<PAD_ELEMS / 8 / 256, 256, 0, stream>>>(in, pad);
    pack_wgt<<<dim3(KTOT / 32, COUT / 32), 256, 0, stream>>>(wgt, wt);

    conv_mfma<<<NBLK, 512, 0, stream>>>(pad, wt, bias, out);
}